// Round 1
// baseline (490.932 us; speedup 1.0000x reference)
//
#include <hip/hip_runtime.h>

typedef unsigned short u16;
typedef __attribute__((ext_vector_type(8))) short s16x8;
typedef __attribute__((ext_vector_type(4))) float f32x4;
typedef __attribute__((ext_vector_type(4))) unsigned short u16x4;

#define DIMSZ 2048
#define NH    16
#define NKV   4
#define SEQ   2048
#define BB    2
#define HD    128
#define REPF  4
#define SCALE 0.08838834764831845f

__device__ __forceinline__ u16 f2bf(float x) {
  union { float f; unsigned u; } v; v.f = x;
  unsigned r = v.u + 0x7fffu + ((v.u >> 16) & 1u);
  return (u16)(r >> 16);
}
__device__ __forceinline__ float bf2f(u16 x) {
  union { unsigned u; float f; } v; v.u = ((unsigned)x) << 16;
  return v.f;
}
__device__ __forceinline__ void gld16(const void* g, void* l) {
  __builtin_amdgcn_global_load_lds(
      (const __attribute__((address_space(1))) unsigned int*)g,
      (__attribute__((address_space(3))) unsigned int*)l, 16, 0, 0);
}

// ---------------- x f32 -> bf16 ----------------
__global__ __launch_bounds__(256) void k_cvt(const float* __restrict__ x,
                                             u16* __restrict__ o) {
  int i = (blockIdx.x * 256 + threadIdx.x) * 8;
  float4 a = *(const float4*)(x + i);
  float4 b = *(const float4*)(x + i + 4);
  u16x4 p0 = { f2bf(a.x), f2bf(a.y), f2bf(a.z), f2bf(a.w) };
  u16x4 p1 = { f2bf(b.x), f2bf(b.y), f2bf(b.z), f2bf(b.w) };
  *(u16x4*)(o + i) = p0;
  *(u16x4*)(o + i + 4) = p1;
}

// ---------------- W [K][N] f32 -> Wt [N][K] bf16 ----------------
__global__ __launch_bounds__(256) void k_transpose(const float* __restrict__ W,
                                                   u16* __restrict__ Wt,
                                                   int K, int N) {
  __shared__ float t[32][33];
  int tx = threadIdx.x & 31, ty = threadIdx.x >> 5;
  int r0 = blockIdx.y * 32, c0 = blockIdx.x * 32;
#pragma unroll
  for (int i = 0; i < 32; i += 8)
    t[ty + i][tx] = W[(size_t)(r0 + ty + i) * N + c0 + tx];
  __syncthreads();
#pragma unroll
  for (int i = 0; i < 32; i += 8)
    Wt[(size_t)(c0 + ty + i) * K + r0 + tx] = f2bf(t[tx][ty + i]);
}

// ---------------- GEMM: A[M][K] bf16 x Bt[N][K] bf16 -> C ----------------
// mode 0: bf16 row-major [M][N]; mode 1: f32 [M][N]; mode 2: V^T [B][KV][HD][SEQ]
__global__ __launch_bounds__(256) void k_gemm(const u16* __restrict__ A,
                                              const u16* __restrict__ Bt,
                                              void* __restrict__ Cout,
                                              int M, int N, int K, int mode) {
  __shared__ __align__(16) u16 shA[128 * 64];
  __shared__ __align__(16) u16 shB[128 * 64];
  const int tid = threadIdx.x;
  const int wave = tid >> 6, lane = tid & 63;
  const int l15 = lane & 15, lh = lane >> 4;
  const int m0 = blockIdx.y * 128, n0 = blockIdx.x * 128;
  const int wr = wave >> 1, wc = wave & 1;

  // staging: wave stages rows [wave*32, +32); 8 lanes per 128B row
  const int lrow = lane >> 3, lg = lane & 7;
  const int sg = (lg ^ lrow) * 8;  // swizzled source elem offset (row&7 == lrow)
  const u16* gA[4]; const u16* gB[4];
  u16* lA[4]; u16* lB[4];
#pragma unroll
  for (int t = 0; t < 4; t++) {
    int row = wave * 32 + t * 8 + lrow;
    gA[t] = A + (size_t)(m0 + row) * K + sg;
    gB[t] = Bt + (size_t)(n0 + row) * K + sg;
    lA[t] = &shA[(wave * 32 + t * 8) * 64];  // wave-uniform LDS base
    lB[t] = &shB[(wave * 32 + t * 8) * 64];
  }

  f32x4 acc[4][4] = {};
  for (int k0 = 0; k0 < K; k0 += 64) {
#pragma unroll
    for (int t = 0; t < 4; t++) {
      gld16(gA[t] + k0, lA[t]);
      gld16(gB[t] + k0, lB[t]);
    }
    __syncthreads();
#pragma unroll
    for (int kf = 0; kf < 2; kf++) {
      s16x8 af[4], bfr[4];
#pragma unroll
      for (int i = 0; i < 4; i++) {
        int rowa = wr * 64 + i * 16 + l15;
        af[i] = *(const s16x8*)&shA[rowa * 64 + (((kf * 4 + lh) ^ (l15 & 7)) * 8)];
        int rowb = wc * 64 + i * 16 + l15;
        bfr[i] = *(const s16x8*)&shB[rowb * 64 + (((kf * 4 + lh) ^ (l15 & 7)) * 8)];
      }
#pragma unroll
      for (int i = 0; i < 4; i++)
#pragma unroll
        for (int j = 0; j < 4; j++)
          acc[i][j] = __builtin_amdgcn_mfma_f32_16x16x32_bf16(af[i], bfr[j], acc[i][j], 0, 0, 0);
    }
    __syncthreads();
  }

  if (mode == 0) {
    u16* C = (u16*)Cout;
#pragma unroll
    for (int i = 0; i < 4; i++)
#pragma unroll
      for (int j = 0; j < 4; j++)
#pragma unroll
        for (int r = 0; r < 4; r++) {
          int m = m0 + wr * 64 + i * 16 + lh * 4 + r;
          int n = n0 + wc * 64 + j * 16 + l15;
          C[(size_t)m * N + n] = f2bf(acc[i][j][r]);
        }
  } else if (mode == 1) {
    float* C = (float*)Cout;
#pragma unroll
    for (int i = 0; i < 4; i++)
#pragma unroll
      for (int j = 0; j < 4; j++)
#pragma unroll
        for (int r = 0; r < 4; r++) {
          int m = m0 + wr * 64 + i * 16 + lh * 4 + r;
          int n = n0 + wc * 64 + j * 16 + l15;
          C[(size_t)m * N + n] = acc[i][j][r];
        }
  } else {  // V^T: [B][NKV][HD][SEQ]
    u16* C = (u16*)Cout;
#pragma unroll
    for (int i = 0; i < 4; i++)
#pragma unroll
      for (int j = 0; j < 4; j++) {
        int n = n0 + wc * 64 + j * 16 + l15;
        int kvh = n >> 7, d = n & 127;
        int m = m0 + wr * 64 + i * 16 + lh * 4;  // 4 consecutive s
        int b = m >> 11, s = m & 2047;
        u16x4 pk = { f2bf(acc[i][j][0]), f2bf(acc[i][j][1]),
                     f2bf(acc[i][j][2]), f2bf(acc[i][j][3]) };
        *(u16x4*)&C[(((size_t)b * NKV + kvh) * HD + d) * SEQ + s] = pk;
      }
  }
}

// ---------------- fused RMSNorm + RoPE, in place, one wave per row ----------------
__global__ __launch_bounds__(256) void k_normrope(u16* __restrict__ Q,
                                                  u16* __restrict__ Kb,
                                                  const float* __restrict__ qg,
                                                  const float* __restrict__ kg,
                                                  const float* __restrict__ cosT,
                                                  const float* __restrict__ sinT) {
  int wid = (blockIdx.x * 256 + threadIdx.x) >> 6;
  int lane = threadIdx.x & 63;
  const int NQR = BB * SEQ * NH;
  u16* ptr; const float* g; int s;
  if (wid < NQR) {
    ptr = Q + (size_t)wid * HD; g = qg; s = (wid / NH) % SEQ;
  } else {
    int r2 = wid - NQR;
    ptr = Kb + (size_t)r2 * HD; g = kg; s = (r2 / NKV) % SEQ;
  }
  int d = lane * 2;
  unsigned v = *(const unsigned*)(ptr + d);
  float x0 = bf2f((u16)(v & 0xffff)), x1 = bf2f((u16)(v >> 16));
  float ss = x0 * x0 + x1 * x1;
#pragma unroll
  for (int off = 32; off >= 1; off >>= 1) ss += __shfl_xor(ss, off);
  float rinv = rsqrtf(ss * (1.0f / HD) + 1e-6f);
  float n0 = x0 * rinv * g[d], n1 = x1 * rinv * g[d + 1];
  float p0 = __shfl_xor(n0, 32), p1 = __shfl_xor(n1, 32);
  float r0 = (lane < 32) ? -p0 : p0;
  float r1 = (lane < 32) ? -p1 : p1;
  float2 cc = *(const float2*)&cosT[s * HD + d];
  float2 sn = *(const float2*)&sinT[s * HD + d];
  float o0 = n0 * cc.x + r0 * sn.x, o1 = n1 * cc.y + r1 * sn.y;
  *(unsigned*)(ptr + d) = (unsigned)f2bf(o0) | ((unsigned)f2bf(o1) << 16);
}

// ---------------- flash attention, causal, GQA ----------------
// Q [B][S][H][HD] bf16, Kb [B][S][KV][HD] bf16, Vt [B][KV][HD][S] bf16 -> O [B][S][H][HD] bf16
__global__ __launch_bounds__(256) void k_attn(const u16* __restrict__ Q,
                                              const u16* __restrict__ Kb,
                                              const u16* __restrict__ Vt,
                                              u16* __restrict__ O) {
  __shared__ __align__(16) u16 shK[64 * 128];
  __shared__ __align__(16) u16 shV[128 * 64];
  __shared__ __align__(16) u16 shP[4][16 * 72];
  const int tid = threadIdx.x, wave = tid >> 6, lane = tid & 63;
  const int l15 = lane & 15, lh = lane >> 4;
  const int bh = blockIdx.y, b = bh / NH, h = bh % NH, kvh = h / REPF;
  const int q0 = blockIdx.x * 64;

  // Q fragments straight from global: row = l15, k elems kf*32 + lh*8 ..+7
  const u16* qbase = Q + ((size_t)((size_t)b * SEQ + q0 + wave * 16 + l15) * NH + h) * HD;
  s16x8 qf[4];
#pragma unroll
  for (int kf = 0; kf < 4; kf++) qf[kf] = *(const s16x8*)(qbase + kf * 32 + lh * 8);

  f32x4 oacc[8] = {};
  float m_r[4], l_r[4];
#pragma unroll
  for (int r = 0; r < 4; r++) { m_r[r] = -1e30f; l_r[r] = 0.f; }

  const int ntiles = q0 / 64 + 1;
  const int kq = lane >> 4;                      // K staging: row sub-index
  const int vrl = lane >> 3, vg = lane & 7;      // V staging

  for (int kt = 0; kt < ntiles; kt++) {
    // stage K tile [64][128] (16B granules XOR-swizzled by row&7)
#pragma unroll
    for (int t = 0; t < 4; t++) {
      int row = wave * 16 + t * 4 + kq;
      int srcg = l15 ^ (row & 7);
      gld16(Kb + ((size_t)((size_t)b * SEQ + kt * 64 + row) * NKV + kvh) * HD + srcg * 8,
            &shK[(wave * 16 + t * 4) * 128]);
    }
    // stage V^T tile [128][64]
#pragma unroll
    for (int t = 0; t < 4; t++) {
      int row = wave * 32 + t * 8 + vrl;
      int srcg = vg ^ (row & 7);
      gld16(Vt + ((size_t)((size_t)b * NKV + kvh) * HD + row) * SEQ + kt * 64 + srcg * 8,
            &shV[(wave * 32 + t * 8) * 64]);
    }
    __syncthreads();

    // S = Q K^T for this wave's 16 q rows x 64 kv
    f32x4 sacc[4] = {};
#pragma unroll
    for (int kf = 0; kf < 4; kf++)
#pragma unroll
      for (int nf = 0; nf < 4; nf++) {
        s16x8 kfr = *(const s16x8*)&shK[(nf * 16 + l15) * 128 + (((kf * 4 + lh) ^ (l15 & 7)) * 8)];
        sacc[nf] = __builtin_amdgcn_mfma_f32_16x16x32_bf16(qf[kf], kfr, sacc[nf], 0, 0, 0);
      }

    const bool diag = (kt == ntiles - 1);
#pragma unroll
    for (int r = 0; r < 4; r++) {
      int qrow = q0 + wave * 16 + lh * 4 + r;
      float v0 = sacc[0][r] * SCALE, v1 = sacc[1][r] * SCALE;
      float v2 = sacc[2][r] * SCALE, v3 = sacc[3][r] * SCALE;
      if (diag) {
        if (kt * 64 + 0  + l15 > qrow) v0 = -1e30f;
        if (kt * 64 + 16 + l15 > qrow) v1 = -1e30f;
        if (kt * 64 + 32 + l15 > qrow) v2 = -1e30f;
        if (kt * 64 + 48 + l15 > qrow) v3 = -1e30f;
      }
      float mx = fmaxf(fmaxf(v0, v1), fmaxf(v2, v3));
#pragma unroll
      for (int off = 8; off >= 1; off >>= 1) mx = fmaxf(mx, __shfl_xor(mx, off));
      float mnew = fmaxf(m_r[r], mx);
      float alpha = __expf(m_r[r] - mnew);
      float p0 = __expf(v0 - mnew), p1 = __expf(v1 - mnew);
      float p2 = __expf(v2 - mnew), p3 = __expf(v3 - mnew);
      float rs = p0 + p1 + p2 + p3;
#pragma unroll
      for (int off = 8; off >= 1; off >>= 1) rs += __shfl_xor(rs, off);
      m_r[r] = mnew;
      l_r[r] = l_r[r] * alpha + rs;
      u16* prow = &shP[wave][(lh * 4 + r) * 72];
      prow[0  + l15] = f2bf(p0);
      prow[16 + l15] = f2bf(p1);
      prow[32 + l15] = f2bf(p2);
      prow[48 + l15] = f2bf(p3);
#pragma unroll
      for (int c = 0; c < 8; c++) oacc[c][r] *= alpha;
    }

    asm volatile("s_waitcnt lgkmcnt(0)" ::: "memory");
    __builtin_amdgcn_sched_barrier(0);

    // O += P V
#pragma unroll
    for (int kvf = 0; kvf < 2; kvf++) {
      s16x8 pf = *(const s16x8*)&shP[wave][l15 * 72 + kvf * 32 + lh * 8];
#pragma unroll
      for (int nf = 0; nf < 8; nf++) {
        s16x8 vf = *(const s16x8*)&shV[(nf * 16 + l15) * 64 + (((kvf * 4 + lh) ^ (l15 & 7)) * 8)];
        oacc[nf] = __builtin_amdgcn_mfma_f32_16x16x32_bf16(pf, vf, oacc[nf], 0, 0, 0);
      }
    }
    __syncthreads();
  }

#pragma unroll
  for (int r = 0; r < 4; r++) {
    float inv = 1.0f / l_r[r];
    int s = q0 + wave * 16 + lh * 4 + r;
    u16* orow = O + ((size_t)((size_t)b * SEQ + s) * NH + h) * HD;
#pragma unroll
    for (int nf = 0; nf < 8; nf++)
      orow[nf * 16 + l15] = f2bf(oacc[nf][r] * inv);
  }
}

extern "C" void kernel_launch(void* const* d_in, const int* in_sizes, int n_in,
                              void* d_out, int out_size, void* d_ws, size_t ws_size,
                              hipStream_t stream) {
  const float* x    = (const float*)d_in[0];
  const float* Wq   = (const float*)d_in[1];
  const float* Wk   = (const float*)d_in[2];
  const float* Wv   = (const float*)d_in[3];
  const float* Wo   = (const float*)d_in[4];
  const float* qg   = (const float*)d_in[5];
  const float* kg   = (const float*)d_in[6];
  const float* cosT = (const float*)d_in[7];
  const float* sinT = (const float*)d_in[8];

  char* ws = (char*)d_ws;
  const size_t MB = 1024 * 1024;
  u16* xb  = (u16*)(ws);               // 16MB: x bf16, reused later as attn-out O
  u16* Wqt = (u16*)(ws + 16 * MB);     // 8MB
  u16* Wkt = (u16*)(ws + 24 * MB);     // 2MB
  u16* Wvt = (u16*)(ws + 26 * MB);     // 2MB
  u16* Wot = (u16*)(ws + 28 * MB);     // 8MB
  u16* Qb  = (u16*)(ws + 36 * MB);     // 16MB
  u16* Kbf = (u16*)(ws + 52 * MB);     // 4MB
  u16* Vt  = (u16*)(ws + 56 * MB);     // 4MB  (total 60MB)
  u16* Ob  = xb;                       // xb dead after V-GEMM

  k_cvt<<<4096, 256, 0, stream>>>(x, xb);
  k_transpose<<<dim3(DIMSZ / 32, DIMSZ / 32), 256, 0, stream>>>(Wq, Wqt, DIMSZ, DIMSZ);
  k_transpose<<<dim3(512 / 32, DIMSZ / 32), 256, 0, stream>>>(Wk, Wkt, DIMSZ, 512);
  k_transpose<<<dim3(512 / 32, DIMSZ / 32), 256, 0, stream>>>(Wv, Wvt, DIMSZ, 512);
  k_transpose<<<dim3(DIMSZ / 32, DIMSZ / 32), 256, 0, stream>>>(Wo, Wot, DIMSZ, DIMSZ);

  k_gemm<<<dim3(16, 32), 256, 0, stream>>>(xb, Wqt, Qb, BB * SEQ, DIMSZ, DIMSZ, 0);
  k_gemm<<<dim3(4, 32), 256, 0, stream>>>(xb, Wkt, Kbf, BB * SEQ, 512, DIMSZ, 0);
  k_gemm<<<dim3(4, 32), 256, 0, stream>>>(xb, Wvt, Vt, BB * SEQ, 512, DIMSZ, 2);

  k_normrope<<<20480, 256, 0, stream>>>(Qb, Kbf, qg, kg, cosT, sinT);
  k_attn<<<dim3(SEQ / 64, BB * NH), 256, 0, stream>>>(Qb, Kbf, Vt, Ob);

  k_gemm<<<dim3(16, 32), 256, 0, stream>>>(Ob, Wot, (float*)d_out, BB * SEQ, DIMSZ, DIMSZ, 1);
}

// Round 3
// 352.010 us; speedup vs baseline: 1.3947x; 1.3947x over previous
//
#include <hip/hip_runtime.h>

typedef unsigned short u16;
typedef __attribute__((ext_vector_type(8))) short s16x8;
typedef __attribute__((ext_vector_type(4))) float f32x4;
typedef __attribute__((ext_vector_type(4))) unsigned short u16x4;

#define DIMSZ 2048
#define NH    16
#define NKV   4
#define SEQ   2048
#define BB    2
#define HD    128
#define REPF  4
#define SCALE 0.08838834764831845f

__device__ __forceinline__ u16 f2bf(float x) {
  union { float f; unsigned u; } v; v.f = x;
  unsigned r = v.u + 0x7fffu + ((v.u >> 16) & 1u);
  return (u16)(r >> 16);
}
__device__ __forceinline__ float bf2f(u16 x) {
  union { unsigned u; float f; } v; v.u = ((unsigned)x) << 16;
  return v.f;
}
// round-half-up pack of two f32 -> two bf16 in a u32 (P-probabilities: rounding mode irrelevant)
__device__ __forceinline__ unsigned pack2(float a, float b) {
  union { float f; unsigned u; } x, y; x.f = a; y.f = b;
  return ((x.u + 0x8000u) >> 16) | ((y.u + 0x8000u) & 0xffff0000u);
}
__device__ __forceinline__ void gld16(const void* g, void* l) {
  __builtin_amdgcn_global_load_lds(
      (const __attribute__((address_space(1))) unsigned int*)g,
      (__attribute__((address_space(3))) unsigned int*)l, 16, 0, 0);
}

// ---------------- x f32 -> bf16 ----------------
__global__ __launch_bounds__(256) void k_cvt(const float* __restrict__ x,
                                             u16* __restrict__ o) {
  int i = (blockIdx.x * 256 + threadIdx.x) * 8;
  float4 a = *(const float4*)(x + i);
  float4 b = *(const float4*)(x + i + 4);
  u16x4 p0 = { f2bf(a.x), f2bf(a.y), f2bf(a.z), f2bf(a.w) };
  u16x4 p1 = { f2bf(b.x), f2bf(b.y), f2bf(b.z), f2bf(b.w) };
  *(u16x4*)(o + i) = p0;
  *(u16x4*)(o + i + 4) = p1;
}

// ---------------- W [K][N] f32 -> Wt [N][K] bf16 ----------------
__global__ __launch_bounds__(256) void k_transpose(const float* __restrict__ W,
                                                   u16* __restrict__ Wt,
                                                   int K, int N) {
  __shared__ float t[32][33];
  int tx = threadIdx.x & 31, ty = threadIdx.x >> 5;
  int r0 = blockIdx.y * 32, c0 = blockIdx.x * 32;
#pragma unroll
  for (int i = 0; i < 32; i += 8)
    t[ty + i][tx] = W[(size_t)(r0 + ty + i) * N + c0 + tx];
  __syncthreads();
#pragma unroll
  for (int i = 0; i < 32; i += 8)
    Wt[(size_t)(c0 + ty + i) * K + r0 + tx] = f2bf(t[tx][ty + i]);
}

// ---------------- GEMM: A[M][K] bf16 x Bt[N][K] bf16 ----------------
// mode 1: f32 [M][N] to C0
// mode 3: fused QKV: n in [0,2048) -> C0 bf16 [M][2048]; [2048,2560) -> C1 bf16 [M][512];
//         [2560,3072) -> C2 as V^T [B][KV][HD][SEQ]
__global__ __launch_bounds__(256) void k_gemm(const u16* __restrict__ A,
                                              const u16* __restrict__ Bt,
                                              void* __restrict__ C0,
                                              void* __restrict__ C1,
                                              void* __restrict__ C2,
                                              int M, int N, int K, int mode) {
  __shared__ __align__(16) u16 shA[128 * 64];
  __shared__ __align__(16) u16 shB[128 * 64];
  const int tid = threadIdx.x;
  const int wave = tid >> 6, lane = tid & 63;
  const int l15 = lane & 15, lh = lane >> 4;
  const int m0 = blockIdx.y * 128, n0 = blockIdx.x * 128;
  const int wr = wave >> 1, wc = wave & 1;

  const int lrow = lane >> 3, lg = lane & 7;
  const int sg = (lg ^ lrow) * 8;  // swizzled source granule (row&7 == lrow)
  const u16* gA[4]; const u16* gB[4];
  u16* lA[4]; u16* lB[4];
#pragma unroll
  for (int t = 0; t < 4; t++) {
    int row = wave * 32 + t * 8 + lrow;
    gA[t] = A + (size_t)(m0 + row) * K + sg;
    gB[t] = Bt + (size_t)(n0 + row) * K + sg;
    lA[t] = &shA[(wave * 32 + t * 8) * 64];
    lB[t] = &shB[(wave * 32 + t * 8) * 64];
  }

  f32x4 acc[4][4] = {};
  for (int k0 = 0; k0 < K; k0 += 64) {
#pragma unroll
    for (int t = 0; t < 4; t++) {
      gld16(gA[t] + k0, lA[t]);
      gld16(gB[t] + k0, lB[t]);
    }
    __syncthreads();
#pragma unroll
    for (int kf = 0; kf < 2; kf++) {
      s16x8 af[4], bfr[4];
#pragma unroll
      for (int i = 0; i < 4; i++) {
        int rowa = wr * 64 + i * 16 + l15;
        af[i] = *(const s16x8*)&shA[rowa * 64 + (((kf * 4 + lh) ^ (l15 & 7)) * 8)];
        int rowb = wc * 64 + i * 16 + l15;
        bfr[i] = *(const s16x8*)&shB[rowb * 64 + (((kf * 4 + lh) ^ (l15 & 7)) * 8)];
      }
#pragma unroll
      for (int i = 0; i < 4; i++)
#pragma unroll
        for (int j = 0; j < 4; j++)
          acc[i][j] = __builtin_amdgcn_mfma_f32_16x16x32_bf16(af[i], bfr[j], acc[i][j], 0, 0, 0);
    }
    __syncthreads();
  }

  if (mode == 1) {
    float* C = (float*)C0;
#pragma unroll
    for (int i = 0; i < 4; i++)
#pragma unroll
      for (int j = 0; j < 4; j++)
#pragma unroll
        for (int r = 0; r < 4; r++) {
          int m = m0 + wr * 64 + i * 16 + lh * 4 + r;
          int n = n0 + wc * 64 + j * 16 + l15;
          C[(size_t)m * N + n] = acc[i][j][r];
        }
  } else {  // mode 3: fused QKV epilogue, region selected by n0 (block-uniform)
    if (n0 < 2048) {
      u16* C = (u16*)C0;
#pragma unroll
      for (int i = 0; i < 4; i++)
#pragma unroll
        for (int j = 0; j < 4; j++)
#pragma unroll
          for (int r = 0; r < 4; r++) {
            int m = m0 + wr * 64 + i * 16 + lh * 4 + r;
            int n = n0 + wc * 64 + j * 16 + l15;
            C[(size_t)m * 2048 + n] = f2bf(acc[i][j][r]);
          }
    } else if (n0 < 2560) {
      u16* C = (u16*)C1;
#pragma unroll
      for (int i = 0; i < 4; i++)
#pragma unroll
        for (int j = 0; j < 4; j++)
#pragma unroll
          for (int r = 0; r < 4; r++) {
            int m = m0 + wr * 64 + i * 16 + lh * 4 + r;
            int n = n0 - 2048 + wc * 64 + j * 16 + l15;
            C[(size_t)m * 512 + n] = f2bf(acc[i][j][r]);
          }
    } else {  // V^T: [B][NKV][HD][SEQ]
      u16* C = (u16*)C2;
#pragma unroll
      for (int i = 0; i < 4; i++)
#pragma unroll
        for (int j = 0; j < 4; j++) {
          int n = n0 - 2560 + wc * 64 + j * 16 + l15;
          int kvh = n >> 7, d = n & 127;
          int m = m0 + wr * 64 + i * 16 + lh * 4;
          int b = m >> 11, s = m & 2047;
          u16x4 pk = { f2bf(acc[i][j][0]), f2bf(acc[i][j][1]),
                       f2bf(acc[i][j][2]), f2bf(acc[i][j][3]) };
          *(u16x4*)&C[(((size_t)b * NKV + kvh) * HD + d) * SEQ + s] = pk;
        }
    }
  }
}

// ---------------- fused RMSNorm + RoPE, in place, one wave per row ----------------
__global__ __launch_bounds__(256) void k_normrope(u16* __restrict__ Q,
                                                  u16* __restrict__ Kb,
                                                  const float* __restrict__ qg,
                                                  const float* __restrict__ kg,
                                                  const float* __restrict__ cosT,
                                                  const float* __restrict__ sinT) {
  int wid = (blockIdx.x * 256 + threadIdx.x) >> 6;
  int lane = threadIdx.x & 63;
  const int NQR = BB * SEQ * NH;
  u16* ptr; const float* g; int s;
  if (wid < NQR) {
    ptr = Q + (size_t)wid * HD; g = qg; s = (wid / NH) % SEQ;
  } else {
    int r2 = wid - NQR;
    ptr = Kb + (size_t)r2 * HD; g = kg; s = (r2 / NKV) % SEQ;
  }
  int d = lane * 2;
  unsigned v = *(const unsigned*)(ptr + d);
  float x0 = bf2f((u16)(v & 0xffff)), x1 = bf2f((u16)(v >> 16));
  float ss = x0 * x0 + x1 * x1;
#pragma unroll
  for (int off = 32; off >= 1; off >>= 1) ss += __shfl_xor(ss, off);
  float rinv = rsqrtf(ss * (1.0f / HD) + 1e-6f);
  float2 gv = *(const float2*)&g[d];
  float n0 = x0 * rinv * gv.x, n1 = x1 * rinv * gv.y;
  float p0 = __shfl_xor(n0, 32), p1 = __shfl_xor(n1, 32);
  float r0 = (lane < 32) ? -p0 : p0;
  float r1 = (lane < 32) ? -p1 : p1;
  float2 cc = *(const float2*)&cosT[s * HD + d];
  float2 sn = *(const float2*)&sinT[s * HD + d];
  float o0 = n0 * cc.x + r0 * sn.x, o1 = n1 * cc.y + r1 * sn.y;
  *(unsigned*)(ptr + d) = (unsigned)f2bf(o0) | ((unsigned)f2bf(o1) << 16);
}

// ---------------- flash attention, causal, GQA ----------------
// Swapped-QK^T structure: S^T = mfma(Kfrag, Qfrag) puts a full q-row in each lane
// (q = lane&15, k spread over (lane>>4)*4+reg). Softmax reduce = 2 shfl_xor.
// 2-phase double-buffered K/V staging via global_load_lds.
__global__ __launch_bounds__(256) void k_attn(const u16* __restrict__ Q,
                                              const u16* __restrict__ Kb,
                                              const u16* __restrict__ Vt,
                                              u16* __restrict__ O) {
  __shared__ __align__(16) u16 shK[2][64 * 128];   // [kv][d], row-granule XOR swizzle
  __shared__ __align__(16) u16 shV[2][128 * 64];   // [d][kv], row-granule XOR swizzle
  __shared__ __align__(16) u16 shP[4][16 * 72];    // per-wave P [q=16][kv=64] pad->72
  const int tid = threadIdx.x, wave = tid >> 6, lane = tid & 63;
  const int l15 = lane & 15, lh = lane >> 4;
  const int bid = blockIdx.x;
  const int qt = 31 - (bid >> 5);       // longest-first dispatch
  const int bh = bid & 31, b = bh >> 4, h = bh & 15, kvh = h >> 2;
  const int q0w = qt * 64 + wave * 16;

  // Q fragments from global (row = l15, k = kf*32 + lh*8 ..+7)
  const u16* qbase = Q + ((size_t)((size_t)b * SEQ + q0w + l15) * NH + h) * HD;
  s16x8 qf[4];
#pragma unroll
  for (int kf = 0; kf < 4; kf++) qf[kf] = *(const s16x8*)(qbase + kf * 32 + lh * 8);

  // staging addresses (tile-invariant parts)
  const u16* srcK[4]; const u16* srcV[4];
  int dstK[4], dstV[4];
#pragma unroll
  for (int t = 0; t < 4; t++) {
    int rk = wave * 16 + t * 4 + (lane >> 4);
    int gk = (lane & 15) ^ (rk & 7);
    srcK[t] = Kb + ((size_t)((size_t)b * SEQ + rk) * NKV + kvh) * HD + gk * 8;
    dstK[t] = (wave * 16 + t * 4) * 128;
    int rv = wave * 32 + t * 8 + (lane >> 3);
    int gv = (lane & 7) ^ (rv & 7);
    srcV[t] = Vt + ((size_t)((size_t)b * NKV + kvh) * HD + rv) * SEQ + gv * 8;
    dstV[t] = (wave * 32 + t * 8) * 64;
  }

  f32x4 oacc[8] = {};
  float m = -3e38f, l = 0.f;
  const int nt = qt + 1;
  const float SC2 = SCALE * 1.44269504f;  // exp2 domain

  // prologue: stage tile 0 into buf 0
#pragma unroll
  for (int t = 0; t < 4; t++) {
    gld16(srcK[t], &shK[0][dstK[t]]);
    gld16(srcV[t], &shV[0][dstV[t]]);
  }
  __syncthreads();

  int buf = 0;
  for (int kt = 0; kt < nt; kt++) {
    // issue next tile's staging before compute (2-phase pipeline)
    if (kt + 1 < nt) {
      const size_t koff = (size_t)(kt + 1) * 64;
#pragma unroll
      for (int t = 0; t < 4; t++) {
        gld16(srcK[t] + koff * (NKV * HD), &shK[buf ^ 1][dstK[t]]);
        gld16(srcV[t] + koff, &shV[buf ^ 1][dstV[t]]);
      }
    }

    // S^T = K Q^T : lane holds q = q0w+l15, k = kt*64 + nf*16 + lh*4 + r
    f32x4 sacc[4] = {};
#pragma unroll
    for (int kf = 0; kf < 4; kf++)
#pragma unroll
      for (int nf = 0; nf < 4; nf++) {
        s16x8 kfr = *(const s16x8*)&shK[buf][(nf * 16 + l15) * 128 + (((kf * 4 + lh) ^ (l15 & 7)) * 8)];
        sacc[nf] = __builtin_amdgcn_mfma_f32_16x16x32_bf16(kfr, qf[kf], sacc[nf], 0, 0, 0);
      }

    const int q = q0w + l15;
    float p[4][4];
    float mx = -3e38f;
    if (kt == nt - 1) {
#pragma unroll
      for (int nf = 0; nf < 4; nf++)
#pragma unroll
        for (int r = 0; r < 4; r++) {
          int k = kt * 64 + nf * 16 + lh * 4 + r;
          float s = (k <= q) ? sacc[nf][r] * SC2 : -3e38f;
          p[nf][r] = s; mx = fmaxf(mx, s);
        }
    } else {
#pragma unroll
      for (int nf = 0; nf < 4; nf++)
#pragma unroll
        for (int r = 0; r < 4; r++) {
          float s = sacc[nf][r] * SC2;
          p[nf][r] = s; mx = fmaxf(mx, s);
        }
    }
    mx = fmaxf(mx, __shfl_xor(mx, 16));
    mx = fmaxf(mx, __shfl_xor(mx, 32));

    // defer-max (T13): rescale only when max grew by >8 (log2 domain)
    if (!__all(mx - m <= 8.0f)) {
      float mnew = fmaxf(m, mx);
      float alpha = exp2f(m - mnew);
      l *= alpha; m = mnew;
#pragma unroll
      for (int r = 0; r < 4; r++) {
        float ar = __shfl(alpha, (lh << 2) | r);  // alpha for q-row lh*4+r
#pragma unroll
        for (int nf = 0; nf < 8; nf++) oacc[nf][r] *= ar;
      }
    }

    float rs = 0.f;
#pragma unroll
    for (int nf = 0; nf < 4; nf++)
#pragma unroll
      for (int r = 0; r < 4; r++) {
        float pe = exp2f(p[nf][r] - m);
        p[nf][r] = pe; rs += pe;
      }
    rs += __shfl_xor(rs, 16);
    rs += __shfl_xor(rs, 32);
    l += rs;

    // pack P -> per-wave LDS [q][kv] (8B stores, k-contiguous per q row)
    u16* pw = &shP[wave][l15 * 72];
#pragma unroll
    for (int nf = 0; nf < 4; nf++) {
      uint2 w2 = { pack2(p[nf][0], p[nf][1]), pack2(p[nf][2], p[nf][3]) };
      *(uint2*)(pw + nf * 16 + lh * 4) = w2;
    }
    asm volatile("s_waitcnt lgkmcnt(0)" ::: "memory");
    __builtin_amdgcn_sched_barrier(0);

    // O += P V  (A = P rows q, B = V^T rows d)
#pragma unroll
    for (int kvf = 0; kvf < 2; kvf++) {
      s16x8 pf = *(const s16x8*)&shP[wave][l15 * 72 + kvf * 32 + lh * 8];
#pragma unroll
      for (int nf = 0; nf < 8; nf++) {
        s16x8 vf = *(const s16x8*)&shV[buf][(nf * 16 + l15) * 64 + (((kvf * 4 + lh) ^ (l15 & 7)) * 8)];
        oacc[nf] = __builtin_amdgcn_mfma_f32_16x16x32_bf16(pf, vf, oacc[nf], 0, 0, 0);
      }
    }
    __syncthreads();
    buf ^= 1;
  }

  // epilogue: O[q][d], q = q0w + lh*4 + r, d = nf*16 + l15
#pragma unroll
  for (int r = 0; r < 4; r++) {
    float lv = __shfl(l, (lh << 2) | r);
    float linv = 1.0f / lv;
    int s = q0w + lh * 4 + r;
    u16* orow = O + ((size_t)((size_t)b * SEQ + s) * NH + h) * HD;
#pragma unroll
    for (int nf = 0; nf < 8; nf++)
      orow[nf * 16 + l15] = f2bf(oacc[nf][r] * linv);
  }
}

extern "C" void kernel_launch(void* const* d_in, const int* in_sizes, int n_in,
                              void* d_out, int out_size, void* d_ws, size_t ws_size,
                              hipStream_t stream) {
  const float* x    = (const float*)d_in[0];
  const float* Wq   = (const float*)d_in[1];
  const float* Wk   = (const float*)d_in[2];
  const float* Wv   = (const float*)d_in[3];
  const float* Wo   = (const float*)d_in[4];
  const float* qg   = (const float*)d_in[5];
  const float* kg   = (const float*)d_in[6];
  const float* cosT = (const float*)d_in[7];
  const float* sinT = (const float*)d_in[8];

  char* ws = (char*)d_ws;
  const size_t MB = 1024 * 1024;
  u16* xb    = (u16*)(ws);               // 16MB: x bf16, reused later as attn-out O
  u16* Wqkvt = (u16*)(ws + 16 * MB);     // 12MB: [Wq^T | Wk^T | Wv^T] rows, [3072][2048]
  u16* Wot   = (u16*)(ws + 28 * MB);     // 8MB
  u16* Qb    = (u16*)(ws + 36 * MB);     // 16MB
  u16* Kbf   = (u16*)(ws + 52 * MB);     // 4MB
  u16* Vt    = (u16*)(ws + 56 * MB);     // 4MB  (total 60MB)
  u16* Ob    = xb;                       // xb dead after QKV GEMM

  k_cvt<<<4096, 256, 0, stream>>>(x, xb);
  k_transpose<<<dim3(DIMSZ / 32, DIMSZ / 32), 256, 0, stream>>>(Wq, Wqkvt, DIMSZ, DIMSZ);
  k_transpose<<<dim3(512 / 32, DIMSZ / 32), 256, 0, stream>>>(Wk, Wqkvt + (size_t)2048 * 2048, DIMSZ, 512);
  k_transpose<<<dim3(512 / 32, DIMSZ / 32), 256, 0, stream>>>(Wv, Wqkvt + (size_t)2560 * 2048, DIMSZ, 512);
  k_transpose<<<dim3(DIMSZ / 32, DIMSZ / 32), 256, 0, stream>>>(Wo, Wot, DIMSZ, DIMSZ);

  // fused QKV projection: N = 2048 (Q) + 512 (K) + 512 (V^T epilogue)
  k_gemm<<<dim3(24, 32), 256, 0, stream>>>(xb, Wqkvt, Qb, Kbf, Vt,
                                           BB * SEQ, 3072, DIMSZ, 3);

  k_normrope<<<20480, 256, 0, stream>>>(Qb, Kbf, qg, kg, cosT, sinT);
  k_attn<<<1024, 256, 0, stream>>>(Qb, Kbf, Vt, Ob);

  k_gemm<<<dim3(16, 32), 256, 0, stream>>>(Ob, Wot, (float*)d_out, nullptr, nullptr,
                                           BB * SEQ, DIMSZ, DIMSZ, 1);
}